// Round 10
// baseline (242.737 us; speedup 1.0000x reference)
//
#include <hip/hip_runtime.h>

// out[b,n] = sum_{c,hw} x[b,c,hw] * W_s[n,hw] * W_d[n,c] + W_b[n]
// B=512, C=384, N=512, HW=169 (13x13).
//
// R18: per-CU arithmetic on R17's counters shows the loop is VMEM-issue
// bound: 8 per-lane 16B loads/iter/wave (~16cy each) = ~41us of TA/L1 issue
// per CU vs ~11.5k cy MFMA -> MfmaUtil ~14% (matches R14-R17 exactly).
// Root cause: the wsf B-stream is re-issued per wave (4x) and per block
// (295 MB L1/L2 traffic grid-wide, 2.2x the size of x).
// Fix: B-REUSE ACROSS BATCH. Each block processes a b-PAIR (grid 768):
// same bfr+wdf loads now feed 48 MFMA (2 batches x 2 mi x 6 kb+fold x2).
// Main-loop VMEM instr/CU halves (6.1k -> 3.1k). Registers: a[2][2][6]=96
// + acc 16 + bfr 24 + addr ~25 = ~161 -> (256,3) band (168), no spill.
// red for 2 b at 16 rows would be 64KB, so one shfl_xor(16) per (nf,b)
// folds quad-pairs -> red[2][8][516] = 33KB (3 blocks/CU kept).
// Spill detector: WRITE_SIZE must stay ~3MB.

#define B_   512
#define C_   384
#define N_   512
#define HW_  169
#define CT   128     // c-tile rows (3 c_blks per b)
#define SXR  200     // Xs row stride (v8/fallback kernels)
#define RSTR 516     // red row stride in f32 (512 + 4 pad)

#define WSF_ELEMS  ((size_t)32 * 6 * 64 * 8)       // 98,304 bf16
#define WDF_ELEMS  ((size_t)24 * 32 * 64 * 4)      // 196,608 f32
#define PART_ELEMS ((size_t)3 * B_ * N_)           // 786,432 f32 (3 MB)

typedef __bf16 bf16x8 __attribute__((ext_vector_type(8)));
typedef float f32x4  __attribute__((ext_vector_type(4)));
typedef float f32x4u __attribute__((ext_vector_type(4), aligned(4)));
typedef unsigned u32x4 __attribute__((ext_vector_type(4)));

__device__ __forceinline__ __bf16 f2bf(float f) {
  union { float f; unsigned u; } v; v.f = f;
  unsigned r = (v.u + 0x7FFFu + ((v.u >> 16) & 1u)) >> 16;   // RNE
  unsigned short s = (unsigned short)r;
  return __builtin_bit_cast(__bf16, s);
}

// hi16(a)|hi16(b)<<16 : two bf16 truncations in one v_perm
__device__ __forceinline__ unsigned pack_trunc(float a, float b) {
  return __builtin_amdgcn_perm(__builtin_bit_cast(unsigned, b),
                               __builtin_bit_cast(unsigned, a), 0x07060302u);
}

// ---------------- prep_aux: wsf (B-frag order) + wdf (C-layout order) ----------------
__global__ __launch_bounds__(256)
void prep_aux_kernel(const float* __restrict__ Ws,
                     const float* __restrict__ Wd,
                     __bf16* __restrict__ wsf,
                     float* __restrict__ wdf) {
  int t = blockIdx.x * 256 + threadIdx.x;      // 61440 total, exact
  if (t < 12288) {
    // wsf: t = (nm*6 + kb)*64 + lane ; lane(q=l>>4,m=l&15) holds Ws[nm*16+m][kb*32+q*8+j]
    int lane = t & 63;
    int fr   = t >> 6;
    int kb   = fr % 6;
    int nm   = fr / 6;
    int n    = nm * 16 + (lane & 15);
    int k0   = kb * 32 + (lane >> 4) * 8;
    const float* src = Ws + (size_t)n * HW_;
    bf16x8 v;
    #pragma unroll
    for (int j = 0; j < 8; ++j) {
      int k = k0 + j;
      float f = (k < HW_) ? src[k] : 0.f;
      v[j] = f2bf(f);
    }
    *(bf16x8*)(wsf + (size_t)t * 8) = v;
  } else {
    // wdf: t2 = (cm*32 + nm)*64 + lane; elem i = Wd[nm*16+(l&15)][cm*16+(l>>4)*4+i]
    int t2 = t - 12288;
    int lane = t2 & 63;
    int fr   = t2 >> 6;
    int nm   = fr & 31;
    int cm   = fr >> 5;
    int n    = nm * 16 + (lane & 15);
    int c0   = cm * 16 + (lane >> 4) * 4;
    f32x4 w = *(const f32x4u*)(Wd + (size_t)n * C_ + c0);
    *(f32x4*)(wdf + (size_t)t2 * 4) = w;
  }
}

// ---------------- R18 main kernel: b-PAIR per block, B-stream reused 2x ----------------
__global__ __launch_bounds__(256, 3)       // ~161 total regs -> 168 band
void conv_part(const float* __restrict__ x,
               const __bf16* __restrict__ wsf,
               const float* __restrict__ wdf,
               float* __restrict__ part) {
  __shared__ float red[2 * 8 * RSTR];       // 33 KB — the ONLY LDS

  const int tid  = threadIdx.x;
  // XCD swizzle: the 3 c_blks of one b-pair land on the same id%8 slot.
  const int id    = blockIdx.x;     // 0..767
  const int slot  = id & 7;
  const int t8    = id >> 3;        // 0..95
  const int c_blk = t8 % 3;
  const int bp    = (t8 / 3) * 8 + slot;    // b-pair index 0..255
  const int b0    = bp * 2;

  const int lane  = tid & 63;
  const int wv    = tid >> 6;          // 4 waves; wave owns 32 c-rows (2 frags) x 2 b
  const int lrow  = lane & 15;
  const int lquad = lane >> 4;

  // ---- A-fragments DIRECT from global for BOTH batches: 24 frags ----
  bf16x8 a[2][2][6];                   // [bi][mi][kb] : 96 regs
  #pragma unroll
  for (int bi = 0; bi < 2; ++bi) {
    #pragma unroll
    for (int mi = 0; mi < 2; ++mi) {
      const float* rp = x + ((size_t)(b0 + bi) * C_ + (size_t)c_blk * CT
                             + wv * 32 + mi * 16 + lrow) * HW_;
      #pragma unroll
      for (int kb = 0; kb < 6; ++kb) {
        const int k0 = kb * 32 + lquad * 8;
        float v0, v1, v2, v3, v4, v5, v6, v7;
        if (kb < 5 || k0 + 7 < HW_) {          // kb<=4 always safe (max 159)
          f32x4u t0 = *(const f32x4u*)(rp + k0);
          f32x4u t1 = *(const f32x4u*)(rp + k0 + 4);
          v0 = t0[0]; v1 = t0[1]; v2 = t0[2]; v3 = t0[3];
          v4 = t1[0]; v5 = t1[1]; v6 = t1[2]; v7 = t1[3];
        } else {                               // kb==5 tail: col 168 then pad
          v0 = (k0 + 0 < HW_) ? rp[k0 + 0] : 0.f;
          v1 = v2 = v3 = v4 = v5 = v6 = v7 = 0.f;
        }
        u32x4 pk;
        pk.x = pack_trunc(v0, v1);
        pk.y = pack_trunc(v2, v3);
        pk.z = pack_trunc(v4, v5);
        pk.w = pack_trunc(v6, v7);
        a[bi][mi][kb] = __builtin_bit_cast(bf16x8, pk);
      }
    }
  }

  const int cm0 = c_blk * 8 + wv * 2;       // global 16-c fragment row (0..23)
  const __bf16* bb = wsf + (size_t)lane * 8;
  const float*  wb = wdf + (size_t)lane * 4;
  const f32x4 zero = {0.f, 0.f, 0.f, 0.f};
  // red row for this lane (after quad-pair fold): wv*2 + (lquad>>1)
  const int rrow = wv * 2 + (lquad >> 1);
  const bool wlane = ((lquad & 1) == 0);    // lquad 0,2 write

  // ---- 32 n-fragments: ONE B-load stream feeds both batches ----
  #pragma unroll 1
  for (int nf = 0; nf < 32; ++nf) {
    bf16x8 bfr[6];
    #pragma unroll
    for (int kb = 0; kb < 6; ++kb)
      bfr[kb] = *(const bf16x8*)(bb + ((size_t)nf * 6 + kb) * 512);

    f32x4 w[2];
    #pragma unroll
    for (int mi = 0; mi < 2; ++mi)
      w[mi] = *(const f32x4*)(wb + (((size_t)(cm0 + mi) * 32 + nf) * 256));

    f32x4 acc[2][2] = {{zero, zero}, {zero, zero}};
    #pragma unroll
    for (int kb = 0; kb < 6; ++kb)
      #pragma unroll
      for (int bi = 0; bi < 2; ++bi)
        #pragma unroll
        for (int mi = 0; mi < 2; ++mi)
          acc[bi][mi] = __builtin_amdgcn_mfma_f32_16x16x32_bf16(
              a[bi][mi][kb], bfr[kb], acc[bi][mi], 0, 0, 0);

    // fold acc * W_d per batch; one shfl folds quad-pairs -> 8 red rows/b
    #pragma unroll
    for (int bi = 0; bi < 2; ++bi) {
      float t = 0.f;
      #pragma unroll
      for (int mi = 0; mi < 2; ++mi)
        t += acc[bi][mi][0] * w[mi][0] + acc[bi][mi][1] * w[mi][1]
           + acc[bi][mi][2] * w[mi][2] + acc[bi][mi][3] * w[mi][3];
      t += __shfl_xor(t, 16, 64);            // fold lquad pairs (0,1) and (2,3)
      if (wlane)
        red[(bi * 8 + rrow) * RSTR + nf * 16 + lrow] = t;
    }
  }
  __syncthreads();   // the ONLY barrier

  // ---- combine: 256 threads x 2 n x 2 b; sum 8 red rows each ----
  float* pb = part + ((size_t)c_blk * B_ + b0) * N_;
  #pragma unroll
  for (int r = 0; r < 2; ++r) {
    const int n = r * 256 + tid;
    float v0 = 0.f, v1 = 0.f;
    #pragma unroll
    for (int s = 0; s < 8; ++s) {
      v0 += red[s * RSTR + n];
      v1 += red[(8 + s) * RSTR + n];
    }
    pb[n] = v0;
    pb[N_ + n] = v1;
  }
}

// ---------------- reducer: out = sum of 3 slabs + bias ----------------
__global__ __launch_bounds__(256)
void reduce_part(const float* __restrict__ part,
                 const float* __restrict__ Wb,
                 float* __restrict__ out) {
  const size_t S = (size_t)B_ * N_;
  int idx = (blockIdx.x * 256 + threadIdx.x) * 4;   // 256 blocks -> covers 262144
  f32x4 a0 = *(const f32x4u*)(part + idx);
  f32x4 a1 = *(const f32x4u*)(part + S + idx);
  f32x4 a2 = *(const f32x4u*)(part + 2 * S + idx);
  f32x4 wb = *(const f32x4u*)(Wb + (idx & (N_ - 1)));
  f32x4 r;
  #pragma unroll
  for (int i = 0; i < 4; ++i)
    r[i] = a0[i] + a1[i] + a2[i] + wb[i];
  *(f32x4*)(out + idx) = r;
}

// ---------------- R8 main kernel (ws fits wsf+wdf only; 110 us proven) ----------------
__global__ __launch_bounds__(256, 3)
void conv_fused_v8(const float* __restrict__ x,
                   const __bf16* __restrict__ wsf,
                   const float* __restrict__ wdf,
                   const float* __restrict__ Wb,
                   float* __restrict__ out) {
  __shared__ __align__(16) __bf16 Xs[CT * SXR];   // 51.2 KB
  __shared__ float red[4][64];                     // 1 KB

  const int tid  = threadIdx.x;
  const int id    = blockIdx.x;     // 0..1535
  const int slot  = id & 7;
  const int t8    = id >> 3;        // 0..191
  const int c_blk = t8 % 3;
  const int b     = (t8 / 3) * 8 + slot;

  const int lane  = tid & 63;
  const int wv    = tid >> 6;          // 4 waves: 2x2 (c,n) 64x64 quadrants
  const int cq    = (wv >> 1) * 64;
  const int nq    = (wv & 1) * 64;
  const int lrow  = lane & 15;
  const int lquad = lane >> 4;

  const float* src = x + ((size_t)b * C_ + (size_t)c_blk * CT) * HW_;
  #pragma unroll 4
  for (int p = 0; p < 24; ++p) {
    int i   = p * 256 + tid;
    int row = i / 48;
    int ch  = i - row * 48;
    const float* bp = src + row * HW_ + ch * 4;
    float v0 = 0.f, v1 = 0.f, v2 = 0.f, v3 = 0.f;
    if (ch < 42) {
      f32x4u t = *(const f32x4u*)bp;
      v0 = t[0]; v1 = t[1]; v2 = t[2]; v3 = t[3];
    } else if (ch == 42) {
      v0 = bp[0];
    }
    unsigned d0 = pack_trunc(v0, v1);
    unsigned d1 = pack_trunc(v2, v3);
    uint2 d; d.x = d0; d.y = d1;
    *(uint2*)&Xs[row * SXR + ch * 4] = d;
  }
  __syncthreads();

  const int cm0 = c_blk * 8 + (cq >> 4);

  #pragma unroll 1
  for (int nb = 0; nb < 4; ++nb) {
    const int nm0 = nb * 8 + (nq >> 4);
    const __bf16* bbase = wsf + ((size_t)nm0 * 6) * 512 + (size_t)lane * 8;

    const f32x4 zero = {0.f, 0.f, 0.f, 0.f};
    f32x4 acc[4][4];
    #pragma unroll
    for (int mi = 0; mi < 4; ++mi)
      #pragma unroll
      for (int ni = 0; ni < 4; ++ni)
        acc[mi][ni] = zero;

    #pragma unroll
    for (int kb = 0; kb < 6; ++kb) {
      bf16x8 afr[4], bfr[4];
      #pragma unroll
      for (int mi = 0; mi < 4; ++mi)
        afr[mi] = *(const bf16x8*)&Xs[(cq + mi * 16 + lrow) * SXR + kb * 32 + lquad * 8];
      #pragma unroll
      for (int ni = 0; ni < 4; ++ni)
        bfr[ni] = *(const bf16x8*)(bbase + ((size_t)ni * 6 + kb) * 512);
      #pragma unroll
      for (int mi = 0; mi < 4; ++mi)
        #pragma unroll
        for (int ni = 0; ni < 4; ++ni)
          acc[mi][ni] = __builtin_amdgcn_mfma_f32_16x16x32_bf16(
              afr[mi], bfr[ni], acc[mi][ni], 0, 0, 0);
    }

    float s[4] = {0.f, 0.f, 0.f, 0.f};
    #pragma unroll
    for (int ni = 0; ni < 4; ++ni) {
      #pragma unroll
      for (int mi = 0; mi < 4; ++mi) {
        const f32x4 w = *(const f32x4*)(wdf +
            (((size_t)(cm0 + mi) * 32 + (nm0 + ni)) * 64 + lane) * 4);
        s[ni] += acc[mi][ni][0] * w[0] + acc[mi][ni][1] * w[1]
               + acc[mi][ni][2] * w[2] + acc[mi][ni][3] * w[3];
      }
    }

    #pragma unroll
    for (int ni = 0; ni < 4; ++ni) {
      s[ni] += __shfl_xor(s[ni], 16, 64);
      s[ni] += __shfl_xor(s[ni], 32, 64);
    }
    if (lane < 16) {
      #pragma unroll
      for (int ni = 0; ni < 4; ++ni)
        red[wv][ni * 16 + lrow] = s[ni];
    }
    __syncthreads();

    if (tid < 128) {
      const int half = tid >> 6;
      const int idx  = tid & 63;
      const int n    = nb * 128 + tid;
      float v = red[half][idx] + red[half + 2][idx];
      if (c_blk == 0) v += Wb[n];
      atomicAdd(&out[(size_t)b * N_ + n], v);
    }
    __syncthreads();
  }
}

// ---------------- fallback main kernel (no workspace needed) ----------------

#define LDSS 104
#define KCH  96
#define NT   128

__global__ __launch_bounds__(256)
void conv_main_fallback(const float* __restrict__ x,
                        const float* __restrict__ Ws_g,
                        const float* __restrict__ Wd,
                        const float* __restrict__ Wb,
                        float* __restrict__ out) {
  __shared__ __align__(16) __bf16 Xs[CT][LDSS];
  __shared__ __align__(16) __bf16 Ws[NT][LDSS];

  const int tid   = threadIdx.x;
  const int n_blk = blockIdx.x;
  const int c_blk = blockIdx.y;
  const int b     = blockIdx.z;
  const int c0 = c_blk * CT;
  const int n0 = n_blk * NT;
  const int lane  = tid & 63;
  const int wv    = tid >> 6;
  const int cq    = (wv >> 1) * 64;
  const int nq    = (wv & 1) * 64;
  const int lrow  = lane & 15;
  const int lquad = lane >> 4;

  const f32x4 zero = {0.f, 0.f, 0.f, 0.f};
  f32x4 acc[4][4];
  #pragma unroll
  for (int mi = 0; mi < 4; ++mi)
    #pragma unroll
    for (int ni = 0; ni < 4; ++ni)
      acc[mi][ni] = zero;

  const float* xb  = x    + (size_t)b  * (C_ * HW_) + (size_t)c0 * HW_;
  const float* wsb = Ws_g + (size_t)n0 * HW_;

  for (int ch = 0; ch < 2; ++ch) {
    const int k0 = ch * KCH;
    __syncthreads();
    for (int e = tid; e < CT * KCH; e += 256) {
      int r   = e / KCH;
      int col = e - r * KCH;
      int k   = k0 + col;
      float vx = 0.f, vw = 0.f;
      if (k < HW_) {
        vx = xb [r * HW_ + k];
        vw = wsb[r * HW_ + k];
      }
      Xs[r][col] = f2bf(vx);
      Ws[r][col] = f2bf(vw);
    }
    __syncthreads();

    #pragma unroll
    for (int ks = 0; ks < 3; ++ks) {
      const int kc = ks * 32 + lquad * 8;
      bf16x8 afr[4], bfr[4];
      #pragma unroll
      for (int mi = 0; mi < 4; ++mi)
        afr[mi] = *(const bf16x8*)&Xs[cq + mi * 16 + lrow][kc];
      #pragma unroll
      for (int ni = 0; ni < 4; ++ni)
        bfr[ni] = *(const bf16x8*)&Ws[nq + ni * 16 + lrow][kc];
      #pragma unroll
      for (int mi = 0; mi < 4; ++mi)
        #pragma unroll
        for (int ni = 0; ni < 4; ++ni)
          acc[mi][ni] = __builtin_amdgcn_mfma_f32_16x16x32_bf16(
              afr[mi], bfr[ni], acc[mi][ni], 0, 0, 0);
    }
  }

  #pragma unroll
  for (int ni = 0; ni < 4; ++ni) {
    const int n = n0 + nq + ni * 16 + lrow;
    float sv = 0.f;
    #pragma unroll
    for (int mi = 0; mi < 4; ++mi) {
      const int cbase = c0 + cq + mi * 16 + lquad * 4;
      #pragma unroll
      for (int i = 0; i < 4; ++i)
        sv += acc[mi][ni][i] * Wd[(size_t)n * C_ + (cbase + i)];
    }
    sv += __shfl_xor(sv, 16, 64);
    sv += __shfl_xor(sv, 32, 64);
    if (lane < 16) {
      if (c_blk == 0 && cq == 0) sv += Wb[n];
      atomicAdd(&out[(size_t)b * N_ + n], sv);
    }
  }
}

extern "C" void kernel_launch(void* const* d_in, const int* in_sizes, int n_in,
                              void* d_out, int out_size, void* d_ws, size_t ws_size,
                              hipStream_t stream) {
  const float* x   = (const float*)d_in[0];   // [512,384,13,13]
  const float* Wsp = (const float*)d_in[1];   // [512,13,13]
  const float* Wd  = (const float*)d_in[2];   // [512,384]
  const float* Wb  = (const float*)d_in[3];   // [1,512]
  float* out = (float*)d_out;                 // [512,512] fp32

  const size_t need_basic = WSF_ELEMS * sizeof(__bf16) + WDF_ELEMS * sizeof(float);
  const size_t need_full  = need_basic + PART_ELEMS * sizeof(float);

  if (ws_size >= need_full) {
    __bf16* wsf  = (__bf16*)d_ws;
    float*  wdf  = (float*)(wsf + WSF_ELEMS);
    float*  partb = wdf + WDF_ELEMS;

    prep_aux_kernel<<<240, 256, 0, stream>>>(Wsp, Wd, wsf, wdf);
    conv_part<<<768, 256, 0, stream>>>(x, wsf, wdf, partb);
    reduce_part<<<256, 256, 0, stream>>>(partb, Wb, out);
  } else if (ws_size >= need_basic) {
    __bf16* wsf = (__bf16*)d_ws;
    float*  wdf = (float*)(wsf + WSF_ELEMS);

    hipMemsetAsync(d_out, 0, (size_t)out_size * sizeof(float), stream);
    prep_aux_kernel<<<240, 256, 0, stream>>>(Wsp, Wd, wsf, wdf);
    conv_fused_v8<<<1536, 256, 0, stream>>>(x, wsf, wdf, Wb, out);
  } else {
    hipMemsetAsync(d_out, 0, (size_t)out_size * sizeof(float), stream);
    dim3 grid(N_ / NT, C_ / CT, B_);
    conv_main_fallback<<<grid, 256, 0, stream>>>(x, Wsp, Wd, Wb, out);
  }
}